// Round 5
// baseline (949.234 us; speedup 1.0000x reference)
//
#include <hip/hip_runtime.h>
#include <cmath>

#define IMG_W 512
#define IMG_H 512
#define NIMG 64
#define OWV 502   // valid-conv output extent (SSIM branch)

typedef _Float16 h2 __attribute__((ext_vector_type(2)));
typedef _Float16 h4 __attribute__((ext_vector_type(4)));
typedef float    f2v __attribute__((ext_vector_type(2)));

struct KTaps {
    float kw[11];   // normalized gaussian, win=11, sigma=1.5 (SSIM)
    float ke[13];   // erf-gaussian, 13 taps, NOT normalized (L1)
};

// Zero-cost ordering pin for cross-lane LDS traffic within one wave.
#define WAVE_FENCE() __builtin_amdgcn_wave_barrier()

#if defined(__has_builtin)
#if __has_builtin(__builtin_amdgcn_fdot2)
#define FDOT2(a, b, c) __builtin_amdgcn_fdot2((a), (b), (c), false)
#endif
#endif
#ifndef FDOT2
static __device__ __forceinline__ float fdot2_sw(h2 a, h2 b, float c) {
    return c + (float)a.x * (float)b.x + (float)a.y * (float)b.y;
}
#define FDOT2(a, b, c) fdot2_sw((a), (b), (c))
#endif

static __device__ __forceinline__ h2 lo2(h4 v) { return __builtin_shufflevector(v, v, 0, 1); }
static __device__ __forceinline__ h2 hi2(h4 v) { return __builtin_shufflevector(v, v, 2, 3); }

// ---------------- Kernel A: SSIM -> scalar sum ----------------
// Wave-autonomous, no barriers in loop. 4-quantity trick: stage
// {s=x+y, d=x-y, s^2, d^2}; SSIM needs only conv(s),conv(d),conv(s^2),
// conv(d^2). f16 LDS staging + v_dot2_f32_f16 h-pass, packed-f32 v-ring.
// THIS ROUND: 32-row bands -> 2048 blocks = 8 blocks/CU = 100% occupancy
// (grid was the occupancy cap at 1024 blocks / 50%). VGPR pinned <=64 via
// launch_bounds(256,8). Depth-2 register prefetch, 22-phase unroll.
__global__ __launch_bounds__(256, 8) void ssim_band_kernel(
        const float* __restrict__ x, const float* __restrict__ y,
        double* __restrict__ ssum, KTaps kt) {
    // per-wave dbuf planes of 40 h2 (=80 cols staged, 76 used)
    __shared__ __align__(16) h2 pS[4][2][40], pD[4][2][40],
                               pP[4][2][40], pQ[4][2][40];

    const int img   = blockIdx.z;
    const int band  = blockIdx.y;     // 0..15
    const int strip = blockIdx.x;     // 0..1
    const int tid   = threadIdx.x;
    const int w     = tid >> 6;
    const int lane  = tid & 63;
    const int r0    = band * 32;
    const int wc0   = strip * 256 + w * 64;   // wave's first output col

    const float* __restrict__ xi = x + (size_t)img * IMG_H * IMG_W;
    const float* __restrict__ yi = y + (size_t)img * IMG_H * IMG_W;

    // staging: lanes 0..37 load x,y f2 for cols wc0+2l, wc0+2l+1. OOB->0.
    const bool stg = (lane < 38);
    const int  gc  = wc0 + 2 * lane;
    const bool gok = stg && (gc < IMG_W);

    auto ld2 = [&](const float* __restrict__ p, int r) -> float2 {
        float2 v = make_float2(0.f, 0.f);
        if (gok && r < IMG_H) v = *(const float2*)(p + (size_t)r * IMG_W + gc);
        return v;
    };

    // stage one row: compute s,d,s^2,d^2 once per col, write f16 pairs
    auto stage = [&](int buf, float2 vx, float2 vy) {
        if (stg) {
            const float s0 = vx.x + vy.x, d0 = vx.x - vy.x;
            const float s1 = vx.y + vy.y, d1 = vx.y - vy.y;
            h2 a; a.x = (_Float16)s0;        a.y = (_Float16)s1;        pS[w][buf][lane] = a;
            h2 b; b.x = (_Float16)d0;        b.y = (_Float16)d1;        pD[w][buf][lane] = b;
            h2 c; c.x = (_Float16)(s0 * s0); c.y = (_Float16)(s1 * s1); pP[w][buf][lane] = c;
            h2 d; d.x = (_Float16)(d0 * d0); d.y = (_Float16)(d1 * d1); pQ[w][buf][lane] = d;
        }
    };

    // 4-parity packed f16 weights: window halfs [4a .. 4a+15], a=lane>>2,
    // tap u of output col `lane` sits at j = u + (lane&3).
    const int off = lane & 3;
    h2 w2[8];
#pragma unroll
    for (int t = 0; t < 8; ++t) { w2[t].x = (_Float16)0.f; w2[t].y = (_Float16)0.f; }
#pragma unroll
    for (int offc = 0; offc < 4; ++offc) {
        if (off == offc) {
#pragma unroll
            for (int u = 0; u < 11; ++u) {
                const int j = u + offc;           // compile-time per offc
                if (j & 1) w2[j >> 1].y = (_Float16)kt.kw[u];
                else       w2[j >> 1].x = (_Float16)kt.kw[u];
            }
        }
    }
    const int hb = 2 * (lane >> 2);   // h2-index window base (even)

    f2v acc01[11], acc23[11];
#pragma unroll
    for (int i = 0; i < 11; ++i) { acc01[i] = (f2v)0.f; acc23[i] = (f2v)0.f; }
    float tsum = 0.f;
    const int outc = wc0 + lane;

    // prologue: row r0 -> buf0; depth-2 prefetch r0+1 -> set1, r0+2 -> set0
    stage(0, ld2(xi, r0), ld2(yi, r0));
    float2 pfx[2], pfy[2];
    pfx[1] = ld2(xi, r0 + 1); pfy[1] = ld2(yi, r0 + 1);
    pfx[0] = ld2(xi, r0 + 2); pfy[0] = ld2(yi, r0 + 2);
    WAVE_FENCE();

#pragma unroll 1
    for (int c2 = 0; c2 < 2; ++c2) {
        const int rbase = c2 * 22;
#pragma unroll
        for (int p22 = 0; p22 < 22; ++p22) {
            const int rr  = rbase + p22;    // runtime base + static phase
            const int p11 = p22 % 11;       // static ring phase (22%11==0)
            const int b   = p22 & 1;        // static buffer parity (22 even)
            if (rr <= 41) {
                // h-pass: 4 planes x 4 ds_read_b64 + 8 fdot2 each
                float hS = 0.f, hD = 0.f, hP = 0.f, hQ = 0.f;
#pragma unroll
                for (int k = 0; k < 4; ++k) {
                    const h4 vS = *(const h4*)&pS[w][b][hb + 2 * k];
                    const h4 vD = *(const h4*)&pD[w][b][hb + 2 * k];
                    const h4 vP = *(const h4*)&pP[w][b][hb + 2 * k];
                    const h4 vQ = *(const h4*)&pQ[w][b][hb + 2 * k];
                    hS = FDOT2(w2[2 * k], lo2(vS), hS); hS = FDOT2(w2[2 * k + 1], hi2(vS), hS);
                    hD = FDOT2(w2[2 * k], lo2(vD), hD); hD = FDOT2(w2[2 * k + 1], hi2(vD), hD);
                    hP = FDOT2(w2[2 * k], lo2(vP), hP); hP = FDOT2(w2[2 * k + 1], hi2(vP), hP);
                    hQ = FDOT2(w2[2 * k], lo2(vQ), hQ); hQ = FDOT2(w2[2 * k + 1], hi2(vQ), hQ);
                }
                // stage row rr+1 (loaded 2 iters ago) into other buffer
                if (rr < 41) stage(b ^ 1, pfx[(p22 + 1) & 1], pfy[(p22 + 1) & 1]);
                // reload the just-consumed set with row rr+3 (depth-2)
                if (rr < 39) {
                    pfx[(p22 + 1) & 1] = ld2(xi, r0 + rr + 3);
                    pfy[(p22 + 1) & 1] = ld2(yi, r0 + rr + 3);
                }
                // v-pass: 22 packed FMAs into mod-11 pending slots
                f2v h01; h01.x = hS; h01.y = hD;
                f2v h23; h23.x = hP; h23.y = hQ;
#pragma unroll
                for (int d = 0; d <= 10; ++d) {
                    const int s = (p11 + 11 - d) % 11;
                    f2v wv; wv.x = kt.kw[d]; wv.y = kt.kw[d];
                    acc01[s] += wv * h01;
                    acc23[s] += wv * h23;
                }
                {   // slot (p11+1)%11 completed output row ro = rr-10
                    const int sc = (p11 + 1) % 11;
                    const int ro = rr - 10;
                    if (ro >= 0) {
                        const int o = r0 + ro;
                        if (o < OWV && outc < OWV) {
                            const float S = acc01[sc].x, D = acc01[sc].y;
                            const float P = acc23[sc].x, Q = acc23[sc].y;
                            const float S2 = S * S, D2 = D * D;
                            const float mq2  = 0.5f * (S2 + D2);      // mx^2+my^2
                            const float px2  = 0.5f * (S2 - D2);      // 2 mx my
                            const float vsum = 0.5f * (P + Q) - mq2;  // vx+vy
                            const float cov2 = 0.5f * (P - Q) - px2;  // 2 cov
                            const float c1 = 1e-4f, c2c = 9e-4f;
                            const float num = (px2 + c1) * (cov2 + c2c);
                            const float den = (mq2 + c1) * (vsum + c2c);
                            tsum += num * __builtin_amdgcn_rcpf(den);
                        }
                    }
                    acc01[sc] = (f2v)0.f; acc23[sc] = (f2v)0.f;   // ALWAYS reset
                }
                WAVE_FENCE();
            }
        }
    }

    // reduce + one atomic per block (single real barrier in the kernel)
#pragma unroll
    for (int offr = 32; offr > 0; offr >>= 1) tsum += __shfl_down(tsum, offr, 64);
    __shared__ float wsum[4];
    if (lane == 0) wsum[w] = tsum;
    __syncthreads();
    if (tid == 0) atomicAdd(ssum, (double)(wsum[0] + wsum[1] + wsum[2] + wsum[3]));
}

// ---------------- Kernel B: L1 map + combine ----------------
// Proven R4 geometry (full-width 4-wave blocks, 2 cols/lane, f16 windows,
// float2 stores) but 16-row bands -> 2048 blocks = 8 blocks/CU = 100%
// occupancy, VGPR pinned <=64. 28-iter loop fully unrolled: ring slot,
// buffer parity and prefetch set are all compile-time constants.
__global__ __launch_bounds__(256, 8) void l1_band_kernel(
        const float* __restrict__ x, const float* __restrict__ y,
        const double* __restrict__ ssum, float* __restrict__ out, KTaps kt) {
    __shared__ __align__(16) h2 sdw[4][2][72];   // per-wave dbuf, 70 h2 used

    const int img  = blockIdx.y;
    const int band = blockIdx.x;   // 0..31
    const int tid  = threadIdx.x;
    const int w    = tid >> 6;
    const int lane = tid & 63;
    const int o0   = band * 16;
    const int rin0 = o0 - 6;
    const int wc0  = w * 128;      // wave's first output col

    const float* __restrict__ xi = x + (size_t)img * IMG_H * IMG_W;
    const float* __restrict__ yi = y + (size_t)img * IMG_H * IMG_W;
    float* __restrict__ oi = out + (size_t)img * IMG_H * IMG_W;

    const float base = 100.f * 0.84f * (1.f - (float)(*ssum) * (1.f / 16128256.f));

    // staging: lane l -> local h2 #l (cols 2l,2l+1 of a 140-col tile with
    // 6+6 halo; local col i = global wc0-6+i); lanes 58..63 also h2 #(64+l-58).
    const int  g0  = wc0 - 6 + 2 * lane;
    const bool ok0 = (g0 >= 0) && (g0 < IMG_W);
    const bool on1 = (lane >= 58);
    const int  g1  = wc0 + 6 + 2 * lane;
    const bool ok1 = on1 && (g1 < IMG_W);

    auto ldd = [&](int r, bool ok, int g) -> float2 {   // d = y-x, zero OOB
        float2 v = make_float2(0.f, 0.f);
        if (ok && r >= 0 && r < IMG_H) {
            const float2 a  = *(const float2*)(xi + (size_t)r * IMG_W + g);
            const float2 bb = *(const float2*)(yi + (size_t)r * IMG_W + g);
            v = make_float2(bb.x - a.x, bb.y - a.y);
        }
        return v;
    };
    auto stage = [&](int buf, float2 v0, float2 v1) {
        h2 a; a.x = (_Float16)v0.x; a.y = (_Float16)v0.y;
        sdw[w][buf][lane] = a;
        if (on1) {
            h2 b; b.x = (_Float16)v1.x; b.y = (_Float16)v1.y;
            sdw[w][buf][64 + (lane - 58)] = b;
        }
    };

    // 2-parity packed weights for the column pair (2l, 2l+1):
    // window halfs [2*hb .. 2*hb+15], hb = lane&~1; tap u of col0 at
    // j = u + off (off = 2*(lane&1)), col1 at j = u + off + 1.
    const int off = 2 * (lane & 1);
    h2 wA[8], wB[8];
#pragma unroll
    for (int t = 0; t < 8; ++t) {
        wA[t].x = (_Float16)0.f; wA[t].y = (_Float16)0.f;
        wB[t].x = (_Float16)0.f; wB[t].y = (_Float16)0.f;
    }
#pragma unroll
    for (int offc = 0; offc <= 2; offc += 2) {
        if (off == offc) {
#pragma unroll
            for (int u = 0; u < 13; ++u) {
                const int ja = u + offc;
                if (ja & 1) wA[ja >> 1].y = (_Float16)kt.ke[u];
                else        wA[ja >> 1].x = (_Float16)kt.ke[u];
                const int jb = u + offc + 1;
                if (jb & 1) wB[jb >> 1].y = (_Float16)kt.ke[u];
                else        wB[jb >> 1].x = (_Float16)kt.ke[u];
            }
        }
    }
    const int hb = lane & ~1;   // even h2-index window base

    f2v acc[13];
#pragma unroll
    for (int i = 0; i < 13; ++i) acc[i] = (f2v)0.f;

    // prologue: row rin0 -> buf0; prefetch rin0+1 -> set1, rin0+2 -> set0
    stage(0, ldd(rin0, ok0, g0), ldd(rin0, ok1, g1));
    float2 pf0[2], pf1[2];
    pf0[1] = ldd(rin0 + 1, ok0, g0); pf1[1] = ldd(rin0 + 1, ok1, g1);
    pf0[0] = ldd(rin0 + 2, ok0, g0); pf1[0] = ldd(rin0 + 2, ok1, g1);
    WAVE_FENCE();

    // 28 input rows per band (16 outputs + 12 halo), fully unrolled
#pragma unroll
    for (int rr = 0; rr < 28; ++rr) {
        const int p13 = rr % 13;    // compile-time
        const int b   = rr & 1;     // compile-time
        // h-pass: 4 ds_read_b64 + 16 fdot2 give both columns
        float a0 = 0.f, a1 = 0.f;
#pragma unroll
        for (int k = 0; k < 4; ++k) {
            const h4 v = *(const h4*)&sdw[w][b][hb + 2 * k];
            const h2 vl = lo2(v), vh = hi2(v);
            a0 = FDOT2(wA[2 * k], vl, a0); a0 = FDOT2(wA[2 * k + 1], vh, a0);
            a1 = FDOT2(wB[2 * k], vl, a1); a1 = FDOT2(wB[2 * k + 1], vh, a1);
        }
        if (rr < 27) stage(b ^ 1, pf0[(rr + 1) & 1], pf1[(rr + 1) & 1]);
        if (rr < 25) {
            pf0[(rr + 1) & 1] = ldd(rin0 + rr + 3, ok0, g0);
            pf1[(rr + 1) & 1] = ldd(rin0 + rr + 3, ok1, g1);
        }
        // v-pass: 13 packed FMAs into mod-13 pending slots
        f2v hv; hv.x = a0; hv.y = a1;
#pragma unroll
        for (int d = 0; d <= 12; ++d) {
            const int s = (p13 + 13 - d) % 13;
            f2v wv; wv.x = kt.ke[d]; wv.y = kt.ke[d];
            acc[s] += wv * hv;
        }
        {
            const int sc = (p13 + 1) % 13;
            const int ro = rr - 12;
            if (ro >= 0) {
                const int o = o0 + ro;   // always in [0,511]
                f2v r;
                r.x = fmaf(16.f, fabsf(acc[sc].x), base);
                r.y = fmaf(16.f, fabsf(acc[sc].y), base);
                *(f2v*)&oi[(size_t)o * IMG_W + wc0 + 2 * lane] = r;
            }
            acc[sc] = (f2v)0.f;   // ALWAYS reset
        }
        WAVE_FENCE();
    }
}

extern "C" void kernel_launch(void* const* d_in, const int* in_sizes, int n_in,
                              void* d_out, int out_size, void* d_ws, size_t ws_size,
                              hipStream_t stream) {
    const float* x = (const float*)d_in[0];
    const float* y = (const float*)d_in[1];
    float* out = (float*)d_out;
    double* ssum = (double*)d_ws;

    KTaps kt;
    {   // normalized gaussian win=11 sigma=1.5 (exp-based)
        double g[11], s = 0.0;
        for (int i = 0; i < 11; ++i) {
            const double d = (double)i - 5.0;
            g[i] = std::exp(-(d * d) / 4.5);
            s += g[i];
        }
        for (int i = 0; i < 11; ++i) kt.kw[i] = (float)(g[i] / s);
    }
    {   // erf-gaussian, tail=6 -> 13 taps, sigma=1.5, NOT normalized
        const double t = 0.70710678 / 1.5;
        for (int i = 0; i < 13; ++i) {
            const double xx = (double)i - 6.0;
            const double v = 0.5 * (std::erf(t * (xx + 0.5)) - std::erf(t * (xx - 0.5)));
            kt.ke[i] = (float)(v < 0.0 ? 0.0 : v);
        }
    }

    hipMemsetAsync(ssum, 0, sizeof(double), stream);

    ssim_band_kernel<<<dim3(2, 16, NIMG), dim3(256), 0, stream>>>(x, y, ssum, kt);
    l1_band_kernel<<<dim3(32, NIMG, 1), dim3(256), 0, stream>>>(x, y, ssum, out, kt);
}

// Round 6
// 290.813 us; speedup vs baseline: 3.2641x; 3.2641x over previous
//
#include <hip/hip_runtime.h>
#include <cmath>

#define IMG_W 512
#define IMG_H 512
#define NIMG 64
#define OWV 502   // valid-conv output extent (SSIM branch)

typedef _Float16 h2 __attribute__((ext_vector_type(2)));
typedef _Float16 h4 __attribute__((ext_vector_type(4)));
typedef float    f2v __attribute__((ext_vector_type(2)));

struct KTaps {
    float kw[11];   // normalized gaussian, win=11, sigma=1.5 (SSIM)
    float ke[13];   // erf-gaussian, 13 taps, NOT normalized (L1)
};

// Zero-cost ordering pin for cross-lane LDS traffic within one wave.
#define WAVE_FENCE() __builtin_amdgcn_wave_barrier()

#if defined(__has_builtin)
#if __has_builtin(__builtin_amdgcn_fdot2)
#define FDOT2(a, b, c) __builtin_amdgcn_fdot2((a), (b), (c), false)
#endif
#endif
#ifndef FDOT2
static __device__ __forceinline__ float fdot2_sw(h2 a, h2 b, float c) {
    return c + (float)a.x * (float)b.x + (float)a.y * (float)b.y;
}
#define FDOT2(a, b, c) fdot2_sw((a), (b), (c))
#endif

static __device__ __forceinline__ h2 lo2(h4 v) { return __builtin_shufflevector(v, v, 0, 1); }
static __device__ __forceinline__ h2 hi2(h4 v) { return __builtin_shufflevector(v, v, 2, 3); }

// ---------------- Kernel A: SSIM -> scalar sum ----------------
// Wave-autonomous, no barriers in loop. 4-quantity trick: stage
// {s=x+y, d=x-y, s^2, d^2}; SSIM needs only conv(s),conv(d),conv(s^2),
// conv(d^2). f16 LDS staging + v_dot2_f32_f16 h-pass, packed-f32 v-ring.
// Grid: 32-row bands -> 2048 blocks = 8 blocks/CU (occupancy was grid-
// capped at 1024 blocks). NO launch-bounds waves pin: R5 proved pinning
// 8 waves/EU spills the 44-VGPR ring to scratch (1.7 GB fetch, 5.5x
// regression). R4 proved default bounds compile this body to 60 VGPR,
// which already permits 8 waves/SIMD. Depth-2 prefetch, 22-phase unroll.
__global__ __launch_bounds__(256) void ssim_band_kernel(
        const float* __restrict__ x, const float* __restrict__ y,
        double* __restrict__ ssum, KTaps kt) {
    // per-wave dbuf planes of 40 h2 (=80 cols staged, 76 used)
    __shared__ __align__(16) h2 pS[4][2][40], pD[4][2][40],
                               pP[4][2][40], pQ[4][2][40];

    const int img   = blockIdx.z;
    const int band  = blockIdx.y;     // 0..15
    const int strip = blockIdx.x;     // 0..1
    const int tid   = threadIdx.x;
    const int w     = tid >> 6;
    const int lane  = tid & 63;
    const int r0    = band * 32;
    const int wc0   = strip * 256 + w * 64;   // wave's first output col

    const float* __restrict__ xi = x + (size_t)img * IMG_H * IMG_W;
    const float* __restrict__ yi = y + (size_t)img * IMG_H * IMG_W;

    // staging: lanes 0..37 load x,y f2 for cols wc0+2l, wc0+2l+1. OOB->0.
    const bool stg = (lane < 38);
    const int  gc  = wc0 + 2 * lane;
    const bool gok = stg && (gc < IMG_W);

    auto ld2 = [&](const float* __restrict__ p, int r) -> float2 {
        float2 v = make_float2(0.f, 0.f);
        if (gok && r < IMG_H) v = *(const float2*)(p + (size_t)r * IMG_W + gc);
        return v;
    };

    // stage one row: compute s,d,s^2,d^2 once per col, write f16 pairs
    auto stage = [&](int buf, float2 vx, float2 vy) {
        if (stg) {
            const float s0 = vx.x + vy.x, d0 = vx.x - vy.x;
            const float s1 = vx.y + vy.y, d1 = vx.y - vy.y;
            h2 a; a.x = (_Float16)s0;        a.y = (_Float16)s1;        pS[w][buf][lane] = a;
            h2 b; b.x = (_Float16)d0;        b.y = (_Float16)d1;        pD[w][buf][lane] = b;
            h2 c; c.x = (_Float16)(s0 * s0); c.y = (_Float16)(s1 * s1); pP[w][buf][lane] = c;
            h2 d; d.x = (_Float16)(d0 * d0); d.y = (_Float16)(d1 * d1); pQ[w][buf][lane] = d;
        }
    };

    // 4-parity packed f16 weights: window halfs [4a .. 4a+15], a=lane>>2,
    // tap u of output col `lane` sits at j = u + (lane&3).
    const int off = lane & 3;
    h2 w2[8];
#pragma unroll
    for (int t = 0; t < 8; ++t) { w2[t].x = (_Float16)0.f; w2[t].y = (_Float16)0.f; }
#pragma unroll
    for (int offc = 0; offc < 4; ++offc) {
        if (off == offc) {
#pragma unroll
            for (int u = 0; u < 11; ++u) {
                const int j = u + offc;           // compile-time per offc
                if (j & 1) w2[j >> 1].y = (_Float16)kt.kw[u];
                else       w2[j >> 1].x = (_Float16)kt.kw[u];
            }
        }
    }
    const int hb = 2 * (lane >> 2);   // h2-index window base (even)

    f2v acc01[11], acc23[11];
#pragma unroll
    for (int i = 0; i < 11; ++i) { acc01[i] = (f2v)0.f; acc23[i] = (f2v)0.f; }
    float tsum = 0.f;
    const int outc = wc0 + lane;

    // prologue: row r0 -> buf0; depth-2 prefetch r0+1 -> set1, r0+2 -> set0
    stage(0, ld2(xi, r0), ld2(yi, r0));
    float2 pfx[2], pfy[2];
    pfx[1] = ld2(xi, r0 + 1); pfy[1] = ld2(yi, r0 + 1);
    pfx[0] = ld2(xi, r0 + 2); pfy[0] = ld2(yi, r0 + 2);
    WAVE_FENCE();

#pragma unroll 1
    for (int c2 = 0; c2 < 2; ++c2) {
        const int rbase = c2 * 22;
#pragma unroll
        for (int p22 = 0; p22 < 22; ++p22) {
            const int rr  = rbase + p22;    // runtime base + static phase
            const int p11 = p22 % 11;       // static ring phase (22%11==0)
            const int b   = p22 & 1;        // static buffer parity (22 even)
            if (rr <= 41) {
                // h-pass: 4 planes x 4 ds_read_b64 + 8 fdot2 each
                float hS = 0.f, hD = 0.f, hP = 0.f, hQ = 0.f;
#pragma unroll
                for (int k = 0; k < 4; ++k) {
                    const h4 vS = *(const h4*)&pS[w][b][hb + 2 * k];
                    const h4 vD = *(const h4*)&pD[w][b][hb + 2 * k];
                    const h4 vP = *(const h4*)&pP[w][b][hb + 2 * k];
                    const h4 vQ = *(const h4*)&pQ[w][b][hb + 2 * k];
                    hS = FDOT2(w2[2 * k], lo2(vS), hS); hS = FDOT2(w2[2 * k + 1], hi2(vS), hS);
                    hD = FDOT2(w2[2 * k], lo2(vD), hD); hD = FDOT2(w2[2 * k + 1], hi2(vD), hD);
                    hP = FDOT2(w2[2 * k], lo2(vP), hP); hP = FDOT2(w2[2 * k + 1], hi2(vP), hP);
                    hQ = FDOT2(w2[2 * k], lo2(vQ), hQ); hQ = FDOT2(w2[2 * k + 1], hi2(vQ), hQ);
                }
                // stage row rr+1 (loaded 2 iters ago) into other buffer
                if (rr < 41) stage(b ^ 1, pfx[(p22 + 1) & 1], pfy[(p22 + 1) & 1]);
                // reload the just-consumed set with row rr+3 (depth-2)
                if (rr < 39) {
                    pfx[(p22 + 1) & 1] = ld2(xi, r0 + rr + 3);
                    pfy[(p22 + 1) & 1] = ld2(yi, r0 + rr + 3);
                }
                // v-pass: 22 packed FMAs into mod-11 pending slots
                f2v h01; h01.x = hS; h01.y = hD;
                f2v h23; h23.x = hP; h23.y = hQ;
#pragma unroll
                for (int d = 0; d <= 10; ++d) {
                    const int s = (p11 + 11 - d) % 11;
                    f2v wv; wv.x = kt.kw[d]; wv.y = kt.kw[d];
                    acc01[s] += wv * h01;
                    acc23[s] += wv * h23;
                }
                {   // slot (p11+1)%11 completed output row ro = rr-10
                    const int sc = (p11 + 1) % 11;
                    const int ro = rr - 10;
                    if (ro >= 0) {
                        const int o = r0 + ro;
                        if (o < OWV && outc < OWV) {
                            const float S = acc01[sc].x, D = acc01[sc].y;
                            const float P = acc23[sc].x, Q = acc23[sc].y;
                            const float S2 = S * S, D2 = D * D;
                            const float mq2  = 0.5f * (S2 + D2);      // mx^2+my^2
                            const float px2  = 0.5f * (S2 - D2);      // 2 mx my
                            const float vsum = 0.5f * (P + Q) - mq2;  // vx+vy
                            const float cov2 = 0.5f * (P - Q) - px2;  // 2 cov
                            const float c1 = 1e-4f, c2c = 9e-4f;
                            const float num = (px2 + c1) * (cov2 + c2c);
                            const float den = (mq2 + c1) * (vsum + c2c);
                            tsum += num * __builtin_amdgcn_rcpf(den);
                        }
                    }
                    acc01[sc] = (f2v)0.f; acc23[sc] = (f2v)0.f;   // ALWAYS reset
                }
                WAVE_FENCE();
            }
        }
    }

    // reduce + one atomic per block (single real barrier in the kernel)
#pragma unroll
    for (int offr = 32; offr > 0; offr >>= 1) tsum += __shfl_down(tsum, offr, 64);
    __shared__ float wsum[4];
    if (lane == 0) wsum[w] = tsum;
    __syncthreads();
    if (tid == 0) atomicAdd(ssum, (double)(wsum[0] + wsum[1] + wsum[2] + wsum[3]));
}

// ---------------- Kernel B: L1 map + combine ----------------
// Full-width 4-wave blocks, 2 cols/lane, f16 windows, float2 stores.
// 16-row bands -> 2048 blocks = 8 blocks/CU. NO waves pin (see kernel A
// comment: pinning caused scratch spill in R5). 28-iter loop fully
// unrolled: ring slot, buffer parity, prefetch set all constant-fold.
__global__ __launch_bounds__(256) void l1_band_kernel(
        const float* __restrict__ x, const float* __restrict__ y,
        const double* __restrict__ ssum, float* __restrict__ out, KTaps kt) {
    __shared__ __align__(16) h2 sdw[4][2][72];   // per-wave dbuf, 70 h2 used

    const int img  = blockIdx.y;
    const int band = blockIdx.x;   // 0..31
    const int tid  = threadIdx.x;
    const int w    = tid >> 6;
    const int lane = tid & 63;
    const int o0   = band * 16;
    const int rin0 = o0 - 6;
    const int wc0  = w * 128;      // wave's first output col

    const float* __restrict__ xi = x + (size_t)img * IMG_H * IMG_W;
    const float* __restrict__ yi = y + (size_t)img * IMG_H * IMG_W;
    float* __restrict__ oi = out + (size_t)img * IMG_H * IMG_W;

    const float base = 100.f * 0.84f * (1.f - (float)(*ssum) * (1.f / 16128256.f));

    // staging: lane l -> local h2 #l (cols 2l,2l+1 of a 140-col tile with
    // 6+6 halo; local col i = global wc0-6+i); lanes 58..63 also h2 #(64+l-58).
    const int  g0  = wc0 - 6 + 2 * lane;
    const bool ok0 = (g0 >= 0) && (g0 < IMG_W);
    const bool on1 = (lane >= 58);
    const int  g1  = wc0 + 6 + 2 * lane;
    const bool ok1 = on1 && (g1 < IMG_W);

    auto ldd = [&](int r, bool ok, int g) -> float2 {   // d = y-x, zero OOB
        float2 v = make_float2(0.f, 0.f);
        if (ok && r >= 0 && r < IMG_H) {
            const float2 a  = *(const float2*)(xi + (size_t)r * IMG_W + g);
            const float2 bb = *(const float2*)(yi + (size_t)r * IMG_W + g);
            v = make_float2(bb.x - a.x, bb.y - a.y);
        }
        return v;
    };
    auto stage = [&](int buf, float2 v0, float2 v1) {
        h2 a; a.x = (_Float16)v0.x; a.y = (_Float16)v0.y;
        sdw[w][buf][lane] = a;
        if (on1) {
            h2 b; b.x = (_Float16)v1.x; b.y = (_Float16)v1.y;
            sdw[w][buf][64 + (lane - 58)] = b;
        }
    };

    // 2-parity packed weights for the column pair (2l, 2l+1):
    // window halfs [2*hb .. 2*hb+15], hb = lane&~1; tap u of col0 at
    // j = u + off (off = 2*(lane&1)), col1 at j = u + off + 1.
    const int off = 2 * (lane & 1);
    h2 wA[8], wB[8];
#pragma unroll
    for (int t = 0; t < 8; ++t) {
        wA[t].x = (_Float16)0.f; wA[t].y = (_Float16)0.f;
        wB[t].x = (_Float16)0.f; wB[t].y = (_Float16)0.f;
    }
#pragma unroll
    for (int offc = 0; offc <= 2; offc += 2) {
        if (off == offc) {
#pragma unroll
            for (int u = 0; u < 13; ++u) {
                const int ja = u + offc;
                if (ja & 1) wA[ja >> 1].y = (_Float16)kt.ke[u];
                else        wA[ja >> 1].x = (_Float16)kt.ke[u];
                const int jb = u + offc + 1;
                if (jb & 1) wB[jb >> 1].y = (_Float16)kt.ke[u];
                else        wB[jb >> 1].x = (_Float16)kt.ke[u];
            }
        }
    }
    const int hb = lane & ~1;   // even h2-index window base

    f2v acc[13];
#pragma unroll
    for (int i = 0; i < 13; ++i) acc[i] = (f2v)0.f;

    // prologue: row rin0 -> buf0; prefetch rin0+1 -> set1, rin0+2 -> set0
    stage(0, ldd(rin0, ok0, g0), ldd(rin0, ok1, g1));
    float2 pf0[2], pf1[2];
    pf0[1] = ldd(rin0 + 1, ok0, g0); pf1[1] = ldd(rin0 + 1, ok1, g1);
    pf0[0] = ldd(rin0 + 2, ok0, g0); pf1[0] = ldd(rin0 + 2, ok1, g1);
    WAVE_FENCE();

    // 28 input rows per band (16 outputs + 12 halo), fully unrolled
#pragma unroll
    for (int rr = 0; rr < 28; ++rr) {
        const int p13 = rr % 13;    // compile-time
        const int b   = rr & 1;     // compile-time
        // h-pass: 4 ds_read_b64 + 16 fdot2 give both columns
        float a0 = 0.f, a1 = 0.f;
#pragma unroll
        for (int k = 0; k < 4; ++k) {
            const h4 v = *(const h4*)&sdw[w][b][hb + 2 * k];
            const h2 vl = lo2(v), vh = hi2(v);
            a0 = FDOT2(wA[2 * k], vl, a0); a0 = FDOT2(wA[2 * k + 1], vh, a0);
            a1 = FDOT2(wB[2 * k], vl, a1); a1 = FDOT2(wB[2 * k + 1], vh, a1);
        }
        if (rr < 27) stage(b ^ 1, pf0[(rr + 1) & 1], pf1[(rr + 1) & 1]);
        if (rr < 25) {
            pf0[(rr + 1) & 1] = ldd(rin0 + rr + 3, ok0, g0);
            pf1[(rr + 1) & 1] = ldd(rin0 + rr + 3, ok1, g1);
        }
        // v-pass: 13 packed FMAs into mod-13 pending slots
        f2v hv; hv.x = a0; hv.y = a1;
#pragma unroll
        for (int d = 0; d <= 12; ++d) {
            const int s = (p13 + 13 - d) % 13;
            f2v wv; wv.x = kt.ke[d]; wv.y = kt.ke[d];
            acc[s] += wv * hv;
        }
        {
            const int sc = (p13 + 1) % 13;
            const int ro = rr - 12;
            if (ro >= 0) {
                const int o = o0 + ro;   // always in [0,511]
                f2v r;
                r.x = fmaf(16.f, fabsf(acc[sc].x), base);
                r.y = fmaf(16.f, fabsf(acc[sc].y), base);
                *(f2v*)&oi[(size_t)o * IMG_W + wc0 + 2 * lane] = r;
            }
            acc[sc] = (f2v)0.f;   // ALWAYS reset
        }
        WAVE_FENCE();
    }
}

extern "C" void kernel_launch(void* const* d_in, const int* in_sizes, int n_in,
                              void* d_out, int out_size, void* d_ws, size_t ws_size,
                              hipStream_t stream) {
    const float* x = (const float*)d_in[0];
    const float* y = (const float*)d_in[1];
    float* out = (float*)d_out;
    double* ssum = (double*)d_ws;

    KTaps kt;
    {   // normalized gaussian win=11 sigma=1.5 (exp-based)
        double g[11], s = 0.0;
        for (int i = 0; i < 11; ++i) {
            const double d = (double)i - 5.0;
            g[i] = std::exp(-(d * d) / 4.5);
            s += g[i];
        }
        for (int i = 0; i < 11; ++i) kt.kw[i] = (float)(g[i] / s);
    }
    {   // erf-gaussian, tail=6 -> 13 taps, sigma=1.5, NOT normalized
        const double t = 0.70710678 / 1.5;
        for (int i = 0; i < 13; ++i) {
            const double xx = (double)i - 6.0;
            const double v = 0.5 * (std::erf(t * (xx + 0.5)) - std::erf(t * (xx - 0.5)));
            kt.ke[i] = (float)(v < 0.0 ? 0.0 : v);
        }
    }

    hipMemsetAsync(ssum, 0, sizeof(double), stream);

    ssim_band_kernel<<<dim3(2, 16, NIMG), dim3(256), 0, stream>>>(x, y, ssum, kt);
    l1_band_kernel<<<dim3(32, NIMG, 1), dim3(256), 0, stream>>>(x, y, ssum, out, kt);
}

// Round 7
// 271.190 us; speedup vs baseline: 3.5002x; 1.0724x over previous
//
#include <hip/hip_runtime.h>
#include <cmath>

#define IMG_W 512
#define IMG_H 512
#define NIMG 64
#define OWV 502   // valid-conv output extent (SSIM branch)

typedef _Float16 h2 __attribute__((ext_vector_type(2)));
typedef _Float16 h4 __attribute__((ext_vector_type(4)));
typedef _Float16 h8 __attribute__((ext_vector_type(8)));

struct KTaps {
    float kw[11];        // normalized gaussian, win=11, sigma=1.5 (SSIM)
    float ke[13];        // erf-gaussian, 13 taps, NOT normalized (L1)
    unsigned wpk[11][6]; // per-phase rotated packed-f16 vertical weight pairs
};

// Zero-cost ordering pin for cross-lane LDS traffic within one wave.
#define WAVE_FENCE() __builtin_amdgcn_wave_barrier()

#if defined(__has_builtin)
#if __has_builtin(__builtin_amdgcn_fdot2)
#define FDOT2(a, b, c) __builtin_amdgcn_fdot2((a), (b), (c), false)
#endif
#endif
#ifndef FDOT2
static __device__ __forceinline__ float fdot2_sw(h2 a, h2 b, float c) {
    return c + (float)a.x * (float)b.x + (float)a.y * (float)b.y;
}
#define FDOT2(a, b, c) fdot2_sw((a), (b), (c))
#endif

static __device__ __forceinline__ h2 lo2(h4 v) { return __builtin_shufflevector(v, v, 0, 1); }
static __device__ __forceinline__ h2 hi2(h4 v) { return __builtin_shufflevector(v, v, 2, 3); }
static __device__ __forceinline__ h2 upk(unsigned u) {
    union { unsigned u; h2 h; } c; c.u = u; return c.h;
}

// ---------------- Kernel A: SSIM -> scalar sum ----------------
// Wave-autonomous, no barriers in loop. Stage {s=x+y, d=x-y, s^2, d^2} as
// PLANE-INTERLEAVED f16 per column-pair: one 16B half = 4 planes' h2 ->
// h-pass is 6 ds_read_b128 (one base + imm offsets) + 24 fdot2, stage is
// ONE ds_write_b128. Vertical pass: f16 h-VALUE HISTORY (24 h2 regs, was
// a 44-f32 partial-sum ring) + per-completion rotated 11-tap dot with
// phase-static packed weights from kernarg (SGPR). Targets VGPR<=64 so
// the 2048-block grid reaches 8 waves/SIMD (R6 failed at 68 VGPR).
__global__ __launch_bounds__(256) void ssim_band_kernel(
        const float* __restrict__ x, const float* __restrict__ y,
        double* __restrict__ ssum, KTaps kt) {
    // [wave][buf][half][plane] h2 ; half = column pair, planes S,D,P,Q
    __shared__ __align__(16) h2 plq[4][2][40][4];

    const int img   = blockIdx.z;
    const int band  = blockIdx.y;     // 0..15 (32-row bands)
    const int strip = blockIdx.x;     // 0..1
    const int tid   = threadIdx.x;
    const int w     = tid >> 6;
    const int lane  = tid & 63;
    const int r0    = band * 32;
    const int wc0   = strip * 256 + w * 64;   // wave's first output col

    const float* __restrict__ xi = x + (size_t)img * IMG_H * IMG_W;
    const float* __restrict__ yi = y + (size_t)img * IMG_H * IMG_W;

    // staging: lanes 0..37 load x,y f2 for cols wc0+2l, wc0+2l+1. OOB->0.
    const bool stg = (lane < 38);
    const int  gc  = wc0 + 2 * lane;
    const bool gok = stg && (gc < IMG_W);

    auto ld2 = [&](const float* __restrict__ p, int r) -> float2 {
        float2 v = make_float2(0.f, 0.f);
        if (gok && r < IMG_H) v = *(const float2*)(p + (size_t)r * IMG_W + gc);
        return v;
    };

    // stage one row: compute 4 quantities once per col, ONE b128 write
    auto stage = [&](int buf, float2 vx, float2 vy) {
        if (stg) {
            const float s0 = vx.x + vy.x, d0 = vx.x - vy.x;
            const float s1 = vx.y + vy.y, d1 = vx.y - vy.y;
            h8 st;
            st[0] = (_Float16)s0;        st[1] = (_Float16)s1;
            st[2] = (_Float16)d0;        st[3] = (_Float16)d1;
            st[4] = (_Float16)(s0 * s0); st[5] = (_Float16)(s1 * s1);
            st[6] = (_Float16)(d0 * d0); st[7] = (_Float16)(d1 * d1);
            *(h8*)&plq[w][buf][lane][0] = st;
        }
    };

    // 2-parity packed h-weights: window halves H..H+5 (H=lane>>1),
    // tap u of col `lane` at slot j = u + (lane&1), j in [0..11].
    h2 w6[6];
#pragma unroll
    for (int t = 0; t < 6; ++t) { w6[t].x = (_Float16)0.f; w6[t].y = (_Float16)0.f; }
    if (lane & 1) {
#pragma unroll
        for (int u = 0; u < 11; ++u) {
            const int j = u + 1;
            if (j & 1) w6[j >> 1].y = (_Float16)kt.kw[u];
            else       w6[j >> 1].x = (_Float16)kt.kw[u];
        }
    } else {
#pragma unroll
        for (int u = 0; u < 11; ++u) {
            if (u & 1) w6[u >> 1].y = (_Float16)kt.kw[u];
            else       w6[u >> 1].x = (_Float16)kt.kw[u];
        }
    }
    const int H = lane >> 1;   // window base half

    // f16 h-value history: slot s (mod 11) lives in hist*[s>>1] half (s&1)
    h2 histS[6], histD[6], histP[6], histQ[6];
#pragma unroll
    for (int t = 0; t < 6; ++t) {
        histS[t].x = (_Float16)0.f; histS[t].y = (_Float16)0.f;
        histD[t] = histS[t]; histP[t] = histS[t]; histQ[t] = histS[t];
    }

    float tsum = 0.f;
    const int outc = wc0 + lane;

    // prologue: row r0 -> buf0; depth-2 prefetch r0+1 -> set1, r0+2 -> set0
    stage(0, ld2(xi, r0), ld2(yi, r0));
    float2 pfx[2], pfy[2];
    pfx[1] = ld2(xi, r0 + 1); pfy[1] = ld2(yi, r0 + 1);
    pfx[0] = ld2(xi, r0 + 2); pfy[0] = ld2(yi, r0 + 2);
    WAVE_FENCE();

#pragma unroll 1
    for (int c2 = 0; c2 < 2; ++c2) {
        const int rbase = c2 * 22;
#pragma unroll
        for (int p22 = 0; p22 < 22; ++p22) {
            const int rr  = rbase + p22;    // runtime base + static phase
            const int p11 = p22 % 11;       // static ring phase (22%11==0)
            const int b   = p22 & 1;        // static buffer parity (22 even)
            if (rr <= 41) {
                // h-pass: 6 b128 reads (base + imm offsets) + 24 fdot2
                float hS = 0.f, hD = 0.f, hP = 0.f, hQ = 0.f;
#pragma unroll
                for (int i = 0; i < 6; ++i) {
                    const h8 v = *(const h8*)&plq[w][b][H + i][0];
                    const h2 sp = __builtin_shufflevector(v, v, 0, 1);
                    const h2 dp = __builtin_shufflevector(v, v, 2, 3);
                    const h2 pp = __builtin_shufflevector(v, v, 4, 5);
                    const h2 qp = __builtin_shufflevector(v, v, 6, 7);
                    hS = FDOT2(w6[i], sp, hS);
                    hD = FDOT2(w6[i], dp, hD);
                    hP = FDOT2(w6[i], pp, hP);
                    hQ = FDOT2(w6[i], qp, hQ);
                }
                // insert row rr into history slot p11 (static half select)
                if (p11 & 1) {
                    histS[p11 >> 1].y = (_Float16)hS; histD[p11 >> 1].y = (_Float16)hD;
                    histP[p11 >> 1].y = (_Float16)hP; histQ[p11 >> 1].y = (_Float16)hQ;
                } else {
                    histS[p11 >> 1].x = (_Float16)hS; histD[p11 >> 1].x = (_Float16)hD;
                    histP[p11 >> 1].x = (_Float16)hP; histQ[p11 >> 1].x = (_Float16)hQ;
                }
                // stage row rr+1 (loaded 2 iters ago) into other buffer
                if (rr < 41) stage(b ^ 1, pfx[(p22 + 1) & 1], pfy[(p22 + 1) & 1]);
                // reload the just-consumed set with row rr+3 (depth-2)
                if (rr < 39) {
                    pfx[(p22 + 1) & 1] = ld2(xi, r0 + rr + 3);
                    pfy[(p22 + 1) & 1] = ld2(yi, r0 + rr + 3);
                }
                {   // completed output row ro = rr-10: rotated 11-tap dot
                    const int ro = rr - 10;
                    if (ro >= 0) {
                        float S = 0.f, D = 0.f, P = 0.f, Q = 0.f;
#pragma unroll
                        for (int m = 0; m < 6; ++m) {
                            const h2 wr = upk(kt.wpk[p11][m]);   // SGPR, phase-static
                            S = FDOT2(wr, histS[m], S); D = FDOT2(wr, histD[m], D);
                            P = FDOT2(wr, histP[m], P); Q = FDOT2(wr, histQ[m], Q);
                        }
                        const int o = r0 + ro;
                        if (o < OWV && outc < OWV) {
                            const float S2 = S * S, D2 = D * D;
                            const float mq2  = 0.5f * (S2 + D2);      // mx^2+my^2
                            const float px2  = 0.5f * (S2 - D2);      // 2 mx my
                            const float vsum = 0.5f * (P + Q) - mq2;  // vx+vy
                            const float cov2 = 0.5f * (P - Q) - px2;  // 2 cov
                            const float c1 = 1e-4f, c2c = 9e-4f;
                            const float num = (px2 + c1) * (cov2 + c2c);
                            const float den = (mq2 + c1) * (vsum + c2c);
                            tsum += num * __builtin_amdgcn_rcpf(den);
                        }
                    }
                }
                WAVE_FENCE();
            }
        }
    }

    // reduce + one atomic per block (single real barrier in the kernel)
#pragma unroll
    for (int offr = 32; offr > 0; offr >>= 1) tsum += __shfl_down(tsum, offr, 64);
    __shared__ float wsum[4];
    if (lane == 0) wsum[w] = tsum;
    __syncthreads();
    if (tid == 0) atomicAdd(ssum, (double)(wsum[0] + wsum[1] + wsum[2] + wsum[3]));
}

// ---------------- Kernel B: L1 map + combine ----------------
// 1 col/lane, 64-col waves, 2 col-strips x 16 32-row bands x 64 imgs =
// 2048 blocks (halo back to 1.375x, was 1.75x in R6's 16-row bands).
// Tiny register set (13-f32 ring, SGPR v-taps) to land <=64 VGPR ->
// 8 waves/SIMD. 4 ds_read_b64 + 8 fdot2 h-pass, scalar f32 stores.
__global__ __launch_bounds__(256) void l1_band_kernel(
        const float* __restrict__ x, const float* __restrict__ y,
        const double* __restrict__ ssum, float* __restrict__ out, KTaps kt) {
    __shared__ __align__(16) h2 sdw[4][2][40];   // per-wave dbuf, 38 halves used

    const int img   = blockIdx.z;
    const int band  = blockIdx.y;   // 0..15
    const int strip = blockIdx.x;   // 0..1
    const int tid   = threadIdx.x;
    const int w     = tid >> 6;
    const int lane  = tid & 63;
    const int o0    = band * 32;
    const int rin0  = o0 - 6;
    const int wc0   = strip * 256 + w * 64;   // wave's first output col

    const float* __restrict__ xi = x + (size_t)img * IMG_H * IMG_W;
    const float* __restrict__ yi = y + (size_t)img * IMG_H * IMG_W;
    float* __restrict__ oi = out + (size_t)img * IMG_H * IMG_W;

    const float base = 100.f * 0.84f * (1.f - (float)(*ssum) * (1.f / 16128256.f));

    // staging: lanes 0..37 stage d=y-x for local cols 2l,2l+1
    // (local col i = global wc0-6+i; 76 cols = 64 outputs + 6+6 halo)
    const bool stg = (lane < 38);
    const int  gc  = wc0 - 6 + 2 * lane;
    const bool gok = stg && (gc >= 0) && (gc < IMG_W);

    auto ldp = [&](int r) -> float2 {   // d = y-x for this lane's col pair
        float2 v = make_float2(0.f, 0.f);
        if (gok && r >= 0 && r < IMG_H) {
            const float2 a  = *(const float2*)(xi + (size_t)r * IMG_W + gc);
            const float2 bb = *(const float2*)(yi + (size_t)r * IMG_W + gc);
            v = make_float2(bb.x - a.x, bb.y - a.y);
        }
        return v;
    };
    auto stage = [&](int buf, float2 v) {
        if (stg) {
            h2 a; a.x = (_Float16)v.x; a.y = (_Float16)v.y;
            sdw[w][buf][lane] = a;
        }
    };

    // 4-parity packed weights: window local cols lane..lane+12, aligned
    // b64 base half bh = 2*(lane>>2); tap u at slot j = u + (lane&3).
    const int off = lane & 3;
    h2 w2[8];
#pragma unroll
    for (int t = 0; t < 8; ++t) { w2[t].x = (_Float16)0.f; w2[t].y = (_Float16)0.f; }
#pragma unroll
    for (int offc = 0; offc < 4; ++offc) {
        if (off == offc) {
#pragma unroll
            for (int u = 0; u < 13; ++u) {
                const int j = u + offc;
                if (j & 1) w2[j >> 1].y = (_Float16)kt.ke[u];
                else       w2[j >> 1].x = (_Float16)kt.ke[u];
            }
        }
    }
    const int bh = 2 * (lane >> 2);   // even h2 base of the b64 window

    float acc[13];
#pragma unroll
    for (int i = 0; i < 13; ++i) acc[i] = 0.f;

    // prologue: row rin0 -> buf0; prefetch rin0+1 -> set1, rin0+2 -> set0
    stage(0, ldp(rin0));
    float2 pf[2];
    pf[1] = ldp(rin0 + 1);
    pf[0] = ldp(rin0 + 2);
    WAVE_FENCE();

#pragma unroll 1
    for (int c2 = 0; c2 < 2; ++c2) {
        const int rbase = c2 * 26;
#pragma unroll
        for (int p26 = 0; p26 < 26; ++p26) {
            const int rr  = rbase + p26;
            const int p13 = p26 % 13;       // static ring phase (26%13==0)
            const int b   = p26 & 1;        // static buffer parity (26 even)
            if (rr <= 43) {
                // h-pass: 4 ds_read_b64 + 8 fdot2 (one output col)
                float a0 = 0.f;
#pragma unroll
                for (int k = 0; k < 4; ++k) {
                    const h4 v = *(const h4*)&sdw[w][b][bh + 2 * k];
                    a0 = FDOT2(w2[2 * k], lo2(v), a0);
                    a0 = FDOT2(w2[2 * k + 1], hi2(v), a0);
                }
                if (rr < 43) stage(b ^ 1, pf[(p26 + 1) & 1]);
                if (rr < 41) pf[(p26 + 1) & 1] = ldp(rin0 + rr + 3);
                // v-pass: 13 scalar FMAs, SGPR taps, static ring indices
#pragma unroll
                for (int d = 0; d <= 12; ++d)
                    acc[(p13 + 13 - d) % 13] += kt.ke[d] * a0;
                {
                    const int sc = (p13 + 1) % 13;
                    const int ro = rr - 12;
                    if (ro >= 0) {
                        const int o = o0 + ro;   // always in [0,511]
                        oi[(size_t)o * IMG_W + wc0 + lane] =
                            fmaf(16.f, fabsf(acc[sc]), base);
                    }
                    acc[sc] = 0.f;   // ALWAYS reset
                }
                WAVE_FENCE();
            }
        }
    }
}

// host f32 -> f16 bits (RTN-even; weights are all normal-range positives)
static unsigned short f32_to_f16_bits(float f) {
    union { float f; unsigned u; } v; v.f = f;
    const unsigned u = v.u;
    const unsigned s = (u >> 16) & 0x8000u;
    int e = (int)((u >> 23) & 0xff) - 127 + 15;
    unsigned m = u & 0x7fffffu;
    if (e <= 0) return (unsigned short)s;            // flush tiny (unused range)
    if (e >= 31) return (unsigned short)(s | 0x7c00u);
    unsigned h = s | ((unsigned)e << 10) | (m >> 13);
    const unsigned rem = m & 0x1fffu;
    if (rem > 0x1000u || (rem == 0x1000u && (h & 1u))) h++;
    return (unsigned short)h;
}

extern "C" void kernel_launch(void* const* d_in, const int* in_sizes, int n_in,
                              void* d_out, int out_size, void* d_ws, size_t ws_size,
                              hipStream_t stream) {
    const float* x = (const float*)d_in[0];
    const float* y = (const float*)d_in[1];
    float* out = (float*)d_out;
    double* ssum = (double*)d_ws;

    KTaps kt;
    float kwf[11];
    {   // normalized gaussian win=11 sigma=1.5 (exp-based)
        double g[11], s = 0.0;
        for (int i = 0; i < 11; ++i) {
            const double d = (double)i - 5.0;
            g[i] = std::exp(-(d * d) / 4.5);
            s += g[i];
        }
        for (int i = 0; i < 11; ++i) { kwf[i] = (float)(g[i] / s); kt.kw[i] = kwf[i]; }
    }
    {   // erf-gaussian, tail=6 -> 13 taps, sigma=1.5, NOT normalized
        const double t = 0.70710678 / 1.5;
        for (int i = 0; i < 13; ++i) {
            const double xx = (double)i - 6.0;
            const double v = 0.5 * (std::erf(t * (xx + 0.5)) - std::erf(t * (xx - 0.5)));
            kt.ke[i] = (float)(v < 0.0 ? 0.0 : v);
        }
    }
    {   // rotated packed vertical weights: at phase p (= row rr mod 11),
        // history slot s holds tap d(s,p) = (s - p - 1) mod 11 of output rr-10
        for (int p = 0; p < 11; ++p) {
            for (int m = 0; m < 6; ++m) {
                const int s0 = 2 * m, s1 = 2 * m + 1;
                const int d0 = ((s0 - p - 1) % 11 + 11) % 11;
                unsigned lo = f32_to_f16_bits(kwf[d0]);
                unsigned hi = 0;
                if (s1 <= 10) {
                    const int d1 = ((s1 - p - 1) % 11 + 11) % 11;
                    hi = f32_to_f16_bits(kwf[d1]);
                }
                kt.wpk[p][m] = lo | (hi << 16);
            }
        }
    }

    hipMemsetAsync(ssum, 0, sizeof(double), stream);

    ssim_band_kernel<<<dim3(2, 16, NIMG), dim3(256), 0, stream>>>(x, y, ssum, kt);
    l1_band_kernel<<<dim3(2, 16, NIMG), dim3(256), 0, stream>>>(x, y, ssum, out, kt);
}